// Round 6
// baseline (51.769 us; speedup 1.0000x reference)
//
#include <hip/hip_runtime.h>
#include <hip/hip_bf16.h>

// out[b][o] = sum_{i,m} a0[b,i]*D[b,m]*T[i][m][o],  D[b,m]=a1*a2*a3, m=(j,k,l)
// K = 33^4 ~ 1.19M streamed once through v_mfma_f32_32x32x16_bf16.
// 2247 two-wave blocks; wave 0 handles i=0..15, wave 1 handles i=16..32.
// => 4494 waves (4.4/SIMD) to push more requests in flight (latency/queuing).
#define HSZ 32
#define HP1 33
#define M3 35937            // 33^3
#define TI_STRIDE 1149984   // 33^3 * 32 floats (T stride over i)
#define NBLK 2247
#define RED_BLOCKS 32
#define RED_PER 71          // 32*71 = 2272 >= 2247

typedef short bf16x8 __attribute__((ext_vector_type(8)));
typedef float f32x16 __attribute__((ext_vector_type(16)));

__device__ inline short f2bf(float f) {
  __hip_bfloat16 h = __float2bfloat16(f);  // RTNE; compiler pairs into cvt_pk
  return __builtin_bit_cast(short, h);
}

// lane l: bo = l&31 (A-row=b / B-col=o), g = l>>5 (k-group); w = wave (i-half)
__global__ __launch_bounds__(128) void k_main(const float* __restrict__ T,
                                              const float* __restrict__ nh,
                                              float* __restrict__ tiles,
                                              float* __restrict__ out) {
  __shared__ float a0s[HP1 * 32];   // a0s[i*32+b]; row 32 = 1.0 (bias)
  __shared__ float red[2][1024];
  const int tid = (int)threadIdx.x;
  const int w = tid >> 6;
  const int l = tid & 63;
  const int bo = l & 31;
  const int g = l >> 5;
  const int m0 = (int)blockIdx.x * 16;
  const int iBeg = w ? 16 : 0;

  // a0 table into LDS (conflict-free broadcast reads later)
  for (int x = tid; x < HP1 * 32; x += 128) {
    const int i = x >> 5;
    const int b = x & 31;
    a0s[x] = (i < HSZ) ? nh[b * 128 + i] : 1.0f;
  }

  if (blockIdx.x == 0) {
    // zero d_out; k_red (later in stream) accumulates atomically
    const float4 z = make_float4(0.f, 0.f, 0.f, 0.f);
    for (int x = tid; x < 256; x += 128) ((float4*)out)[x] = z;
  }

  // T column offsets (pure arithmetic -> lets first T loads issue early)
  int ioff[8];
  int mcv[8];
#pragma unroll
  for (int e = 0; e < 8; ++e) {
    const int mm = m0 + 8 * g + e;
    const int mc = (mm < M3) ? mm : (M3 - 1);
    mcv[e] = (mm < M3) ? mm : -1;  // -1 marks invalid (df -> 0)
    ioff[e] = mc * 32 + bo;
  }

#define LOADT(buf, row)                               \
  {                                                   \
    const float* Tp = T + (size_t)(row) * TI_STRIDE;  \
    _Pragma("unroll")                                 \
    for (int e = 0; e < 8; ++e) buf[e] = Tp[ioff[e]]; \
  }
#define COMP(buf, av)                                                      \
  {                                                                        \
    bf16x8 af, bfr;                                                        \
    _Pragma("unroll")                                                      \
    for (int e = 0; e < 8; ++e) {                                          \
      af[e] = f2bf((av) * df[e]);                                          \
      bfr[e] = f2bf(buf[e]);                                               \
    }                                                                      \
    acc = __builtin_amdgcn_mfma_f32_32x32x16_bf16(af, bfr, acc, 0, 0, 0);  \
  }

  // issue first three row loads NOW; df gathers fly underneath them
  float t0[8], t1[8], t2[8], t3[8];
  LOADT(t0, iBeg + 0);
  LOADT(t1, iBeg + 1);
  LOADT(t2, iBeg + 2);

  // A-side fragment df[e] = a1*a2*a3 (uncoalesced nh gathers, overlapped)
  float df[8];
#pragma unroll
  for (int e = 0; e < 8; ++e) {
    const int mc = (mcv[e] >= 0) ? mcv[e] : (M3 - 1);
    const int j = mc / 1089;
    const int r = mc - j * 1089;
    const int kk = r / 33;
    const int ll = r - kk * 33;
    const float a1 = (j < HSZ) ? nh[(bo * 4 + 1) * HSZ + j] : 1.0f;
    const float a2 = (kk < HSZ) ? nh[(bo * 4 + 2) * HSZ + kk] : 1.0f;
    const float a3 = (ll < HSZ) ? nh[(bo * 4 + 3) * HSZ + ll] : 1.0f;
    df[e] = (mcv[e] >= 0) ? (a1 * a2 * a3) : 0.0f;
  }
  __syncthreads();  // a0s ready

  f32x16 acc = {};
  float av0 = a0s[(iBeg + 0) * 32 + bo];
  float av1 = a0s[(iBeg + 1) * 32 + bo];
  float av2 = a0s[(iBeg + 2) * 32 + bo];
  float av3;

  // 3 full iterations: computes iBeg..iBeg+11, prefetches up to iBeg+14
  for (int ii = 0; ii < 3; ++ii) {
    const int i = iBeg + 4 * ii;
    LOADT(t3, i + 3);
    av3 = a0s[(i + 3) * 32 + bo];
    COMP(t0, av0);
    LOADT(t0, i + 4);
    av0 = a0s[(i + 4) * 32 + bo];
    COMP(t1, av1);
    LOADT(t1, i + 5);
    av1 = a0s[(i + 5) * 32 + bo];
    COMP(t2, av2);
    LOADT(t2, i + 6);  // wave0 max row 14; wave1 max row 30
    av2 = a0s[(i + 6) * 32 + bo];
    COMP(t3, av3);
  }
  if (w == 0) {
    // buffers hold rows 12,13,14; finish rows 12..15
    LOADT(t3, 15);
    av3 = a0s[15 * 32 + bo];
    COMP(t0, av0);  // 12
    COMP(t1, av1);  // 13
    COMP(t2, av2);  // 14
    COMP(t3, av3);  // 15
  } else {
    // buffers hold rows 28,29,30; finish rows 28..32 (32 = bias row, a0=1)
    LOADT(t3, 31);
    av3 = a0s[31 * 32 + bo];
    COMP(t0, av0);  // 28
    LOADT(t0, 32);
    av0 = a0s[32 * 32 + bo];  // = 1.0
    COMP(t1, av1);  // 29
    COMP(t2, av2);  // 30
    COMP(t3, av3);  // 31
    COMP(t0, av0);  // 32
  }
#undef LOADT
#undef COMP

  // cross-wave reduce in LDS, then one private tile per block.
  // C/D layout: col=lane&31, row=(r&3)+8*(r>>2)+4*(lane>>5)  (m74/m101)
#pragma unroll
  for (int r = 0; r < 16; ++r) {
    const int brow = (r & 3) + 8 * (r >> 2) + 4 * g;
    red[w][brow * 32 + bo] = acc[r];
  }
  __syncthreads();
  float* tp = tiles + (size_t)blockIdx.x * 1024 + tid * 8;
  const float4 p0 = *(const float4*)&red[0][tid * 8];
  const float4 p1 = *(const float4*)&red[1][tid * 8];
  const float4 q0 = *(const float4*)&red[0][tid * 8 + 4];
  const float4 q1 = *(const float4*)&red[1][tid * 8 + 4];
  *(float4*)(tp)     = make_float4(p0.x + p1.x, p0.y + p1.y, p0.z + p1.z, p0.w + p1.w);
  *(float4*)(tp + 4) = make_float4(q0.x + q1.x, q0.y + q1.y, q0.z + q1.z, q0.w + q1.w);
}

// k_red: block q sums contiguous tiles [q*71, q*71+71), 4 atomicAdds/thread.
__global__ __launch_bounds__(256) void k_red(const float* __restrict__ tiles,
                                             float* __restrict__ out) {
  const int q = (int)blockIdx.x;
  const int tid = (int)threadIdx.x;
  const int tBeg = q * RED_PER;
  const int tEnd = (tBeg + RED_PER < NBLK) ? (tBeg + RED_PER) : NBLK;
  float4 s0 = make_float4(0.f, 0.f, 0.f, 0.f);
  float4 s1 = make_float4(0.f, 0.f, 0.f, 0.f);
  int t = tBeg;
  for (; t + 1 < tEnd; t += 2) {
    const float4 v0 = *(const float4*)(tiles + (size_t)t * 1024 + tid * 4);
    const float4 v1 = *(const float4*)(tiles + (size_t)(t + 1) * 1024 + tid * 4);
    s0.x += v0.x; s0.y += v0.y; s0.z += v0.z; s0.w += v0.w;
    s1.x += v1.x; s1.y += v1.y; s1.z += v1.z; s1.w += v1.w;
  }
  if (t < tEnd) {
    const float4 v0 = *(const float4*)(tiles + (size_t)t * 1024 + tid * 4);
    s0.x += v0.x; s0.y += v0.y; s0.z += v0.z; s0.w += v0.w;
  }
  atomicAdd(&out[tid * 4 + 0], s0.x + s1.x);
  atomicAdd(&out[tid * 4 + 1], s0.y + s1.y);
  atomicAdd(&out[tid * 4 + 2], s0.z + s1.z);
  atomicAdd(&out[tid * 4 + 3], s0.w + s1.w);
}

extern "C" void kernel_launch(void* const* d_in, const int* in_sizes, int n_in,
                              void* d_out, int out_size, void* d_ws, size_t ws_size,
                              hipStream_t stream) {
  const float* nh = (const float*)d_in[0];  // [32,4,32]
  const float* T  = (const float*)d_in[1];  // [33,33,33,33,32]
  float* out = (float*)d_out;               // [32,32] fp32
  float* tiles = (float*)d_ws;              // NBLK * 1024 floats = 9.2 MB

  k_main<<<NBLK, 128, 0, stream>>>(T, nh, tiles, out);
  k_red<<<RED_BLOCKS, 256, 0, stream>>>(tiles, out);
}